// Round 8
// baseline (2260.532 us; speedup 1.0000x reference)
//
#include <hip/hip_runtime.h>
#include <math.h>

#define QN 8
#define CN 1024
#define DN 256
#define NROWS 32768
#define RPW 32

#define LOSS_OFF 8388608
#define IDX_OFF  8388609

// ---------------------------------------------------------------------------
// Kernel 1: normalize codebooks, store transposed: cbnt[q][k][c]
// (unchanged from rounds 1-7 — verified correct)
// ---------------------------------------------------------------------------
__global__ void rvq_normalize_cb(const float* __restrict__ cb,
                                 float* __restrict__ cbnt,
                                 float* __restrict__ out) {
    if (blockIdx.x == 0 && threadIdx.x == 0) out[LOSS_OFF] = 0.0f;
    const int wave = threadIdx.x >> 6;
    const int lane = threadIdx.x & 63;
    const int cw = blockIdx.x * 4 + wave;          // 0..8191
    const int q = cw >> 10;
    const int c = cw & (CN - 1);
    float4 v = reinterpret_cast<const float4*>(cb + (size_t)cw * DN)[lane];
    float ss = v.x * v.x + v.y * v.y + v.z * v.z + v.w * v.w;
#pragma unroll
    for (int m = 1; m < 64; m <<= 1) ss += __shfl_xor(ss, m, 64);
    const float inv = 1.0f / fmaxf(sqrtf(ss), 1e-12f);
    float* dst = cbnt + (size_t)q * (DN * CN) + (size_t)(lane * 4) * CN + c;
    dst[0 * CN] = v.x * inv;
    dst[1 * CN] = v.y * inv;
    dst[2 * CN] = v.z * inv;
    dst[3 * CN] = v.w * inv;
}

// async global->LDS, 16B per lane (dest = wave-uniform base + lane*16)
__device__ __forceinline__ void acp16(float* lds_dst, const float* gsrc) {
    __builtin_amdgcn_global_load_lds(
        (const __attribute__((address_space(1))) unsigned int*)gsrc,
        (__attribute__((address_space(3))) unsigned int*)lds_dst, 16, 0, 0);
}

// 8 rows x 16 cods per thread, all accumulators individually named (round-4 shape)
#define DECL_ROW(j) \
    float4 c##j##_0 = make_float4(0.f,0.f,0.f,0.f), \
           c##j##_1 = make_float4(0.f,0.f,0.f,0.f), \
           c##j##_2 = make_float4(0.f,0.f,0.f,0.f), \
           c##j##_3 = make_float4(0.f,0.f,0.f,0.f);

#define FMA_ROW(j, S) \
    c##j##_0.x = fmaf(S, b0.x, c##j##_0.x); c##j##_0.y = fmaf(S, b0.y, c##j##_0.y); \
    c##j##_0.z = fmaf(S, b0.z, c##j##_0.z); c##j##_0.w = fmaf(S, b0.w, c##j##_0.w); \
    c##j##_1.x = fmaf(S, b1.x, c##j##_1.x); c##j##_1.y = fmaf(S, b1.y, c##j##_1.y); \
    c##j##_1.z = fmaf(S, b1.z, c##j##_1.z); c##j##_1.w = fmaf(S, b1.w, c##j##_1.w); \
    c##j##_2.x = fmaf(S, b2.x, c##j##_2.x); c##j##_2.y = fmaf(S, b2.y, c##j##_2.y); \
    c##j##_2.z = fmaf(S, b2.z, c##j##_2.z); c##j##_2.w = fmaf(S, b2.w, c##j##_2.w); \
    c##j##_3.x = fmaf(S, b3.x, c##j##_3.x); c##j##_3.y = fmaf(S, b3.y, c##j##_3.y); \
    c##j##_3.z = fmaf(S, b3.z, c##j##_3.z); c##j##_3.w = fmaf(S, b3.w, c##j##_3.w);

#define KKSTEP(kk) { \
    const float* ap = &At[kt4 + (kk)][rg8]; \
    const float4 a0 = *reinterpret_cast<const float4*>(ap); \
    const float4 a1 = *reinterpret_cast<const float4*>(ap + 4); \
    const float* bp = &Btl[bcur][kk][chb + cg4]; \
    const float4 b0 = *reinterpret_cast<const float4*>(bp); \
    const float4 b1 = *reinterpret_cast<const float4*>(bp + 128); \
    const float4 b2 = *reinterpret_cast<const float4*>(bp + 256); \
    const float4 b3 = *reinterpret_cast<const float4*>(bp + 384); \
    FMA_ROW(0, a0.x) FMA_ROW(1, a0.y) FMA_ROW(2, a0.z) FMA_ROW(3, a0.w) \
    FMA_ROW(4, a1.x) FMA_ROW(5, a1.y) FMA_ROW(6, a1.z) FMA_ROW(7, a1.w) }

#define FOLD_Q(j, qq) { \
    const int cb_ = chb + (qq) * 128 + cg4; \
    if (c##j##_##qq.x > bv) { bv = c##j##_##qq.x; bi = cb_ + 0; } \
    if (c##j##_##qq.y > bv) { bv = c##j##_##qq.y; bi = cb_ + 1; } \
    if (c##j##_##qq.z > bv) { bv = c##j##_##qq.z; bi = cb_ + 2; } \
    if (c##j##_##qq.w > bv) { bv = c##j##_##qq.w; bi = cb_ + 3; } }

// within-thread cods ascend (q then e); strict > keeps first max.
// butterfly masks 1..16 stay inside the 32-lane cod group (never cross row-groups)
#define FOLDROW(j) { \
    float bv = -INFINITY; int bi = 0; \
    FOLD_Q(j, 0) FOLD_Q(j, 1) FOLD_Q(j, 2) FOLD_Q(j, 3) \
    _Pragma("unroll") \
    for (int m = 1; m < 32; m <<= 1) { \
        const float ov = __shfl_xor(bv, m, 64); \
        const int   oi = __shfl_xor(bi, m, 64); \
        if (ov > bv || (ov == bv && oi < bi)) { bv = ov; bi = oi; } } \
    fv##j = bv; fi##j = bi; }

// stage one 4k x 1024c B-tile (16 KiB): 4 acp16/thread, linear LDS dest
#define STAGE(nb, tile) { \
    const float* s_ = cbtq + ((size_t)(tile) << 12) + (t << 2); \
    float* d_ = Bflat + (nb) * 4096 + (t << 2); \
    acp16(d_,        s_); \
    acp16(d_ + 1024, s_ + 1024); \
    acp16(d_ + 2048, s_ + 2048); \
    acp16(d_ + 3072, s_ + 3072); }

// ---------------------------------------------------------------------------
// Kernel 2: persistent RVQ, 256-thread WG owns 32 rows through all 8 stages.
// Full-C single pass per stage (2 cod-halves x 4 row-groups x 32 cod-groups).
// B-tiles: 3-buffer pipeline, counted vmcnt (never 0 in main loop) + raw
// s_barrier — loads for 2 future tiles stay in flight across barriers (T4).
// fmaf chain per (row,cod) is k=0..255 sequential — bit-identical to rounds 2-7.
// ---------------------------------------------------------------------------
__global__ __attribute__((amdgpu_flat_work_group_size(256, 256), amdgpu_waves_per_eu(2, 2)))
void rvq_main(const float* __restrict__ in,
              const float* __restrict__ cb,
              const float* __restrict__ cbnt,
              float* __restrict__ out) {
    __shared__ float At[DN][RPW];        // 32 KiB residual, transposed [k][row]
    __shared__ float Btl[3][4][1024];    // 48 KiB: 3-buf of 4k x 1024c tiles
    float* Bflat = &Btl[0][0][0];
    float* wV   = Bflat;                                  // alias (64 floats)
    int*   wI   = reinterpret_cast<int*>(Bflat + 64);     // alias (64 ints)
    int*   sIdx = reinterpret_cast<int*>(Bflat + 128);    // alias (32 ints)
    float* red  = Bflat + 160;                            // alias (4 floats)

    const int t     = threadIdx.x;
    const int ch    = t >> 7;            // cod half (0: cods 0-511, 1: 512-1023)
    const int chb   = ch << 9;
    const int rg    = (t >> 5) & 3;      // row-group -> rows rg*8..+7
    const int rg8   = rg << 3;
    const int cg    = t & 31;            // cod-group within half
    const int cg4   = cg << 2;
    const int r32   = t & 31;            // row for elementwise phases
    const int kpart = t >> 5;            // 0..7 -> k-slice kpart*32..+32
    const int wbase = (ch << 5) + rg8;
    const int base  = blockIdx.x * RPW;

    // residual := inputs
#pragma unroll
    for (int i = 0; i < 8; ++i) {
        const int k0 = (kpart << 5) + (i << 2);
        const float4 v = *reinterpret_cast<const float4*>(in + (size_t)(base + r32) * DN + k0);
        At[k0 + 0][r32] = v.x;
        At[k0 + 1][r32] = v.y;
        At[k0 + 2][r32] = v.z;
        At[k0 + 3][r32] = v.w;
    }
    __syncthreads();

    float lossAcc = 0.0f;

    for (int q = 0; q < QN; ++q) {
        const float* cbq  = cb   + (size_t)q * (CN * DN);
        const float* cbtq = cbnt + (size_t)q * (DN * CN);

        DECL_ROW(0) DECL_ROW(1) DECL_ROW(2) DECL_ROW(3)
        DECL_ROW(4) DECL_ROW(5) DECL_ROW(6) DECL_ROW(7)

        // pipeline prologue: tiles 0,1 in flight (8 outstanding loads/wave)
        STAGE(0, 0)
        STAGE(1, 1)

        int bcur = 0;                    // buffer holding tile tt
        int bst  = 2;                    // buffer for tile tt+2
        for (int tt = 0; tt < 63; ++tt) {
            asm volatile("s_waitcnt vmcnt(4)" ::: "memory");  // tile tt landed; tt+1 in flight
            __builtin_amdgcn_s_barrier();                      // all waves' tt loads visible
            __builtin_amdgcn_sched_barrier(0);
            if (tt < 62) { STAGE(bst, tt + 2) }                // safe: buf last read as tt-1
            const int kt4 = tt << 2;
            KKSTEP(0) KKSTEP(1) KKSTEP(2) KKSTEP(3)
            bcur = (bcur == 2) ? 0 : bcur + 1;
            bst  = (bst  == 2) ? 0 : bst  + 1;
        }
        asm volatile("s_waitcnt vmcnt(0)" ::: "memory");       // drain last tile (once/stage)
        __builtin_amdgcn_s_barrier();
        __builtin_amdgcn_sched_barrier(0);
        {
            const int kt4 = 63 << 2;                           // bcur == 0 here (63%3)
            KKSTEP(0) KKSTEP(1) KKSTEP(2) KKSTEP(3)
        }

        // per-row argmax: fold 16 cods + 5-step butterfly over the 32 cod-lanes
        float fv0, fv1, fv2, fv3, fv4, fv5, fv6, fv7;
        int   fi0, fi1, fi2, fi3, fi4, fi5, fi6, fi7;
        FOLDROW(0) FOLDROW(1) FOLDROW(2) FOLDROW(3)
        FOLDROW(4) FOLDROW(5) FOLDROW(6) FOLDROW(7)

        __syncthreads();                 // compute done everywhere; Btl reusable as scratch
        if (cg == 0) { wV[wbase + 0] = fv0; wI[wbase + 0] = fi0; }
        if (cg == 1) { wV[wbase + 1] = fv1; wI[wbase + 1] = fi1; }
        if (cg == 2) { wV[wbase + 2] = fv2; wI[wbase + 2] = fi2; }
        if (cg == 3) { wV[wbase + 3] = fv3; wI[wbase + 3] = fi3; }
        if (cg == 4) { wV[wbase + 4] = fv4; wI[wbase + 4] = fi4; }
        if (cg == 5) { wV[wbase + 5] = fv5; wI[wbase + 5] = fi5; }
        if (cg == 6) { wV[wbase + 6] = fv6; wI[wbase + 6] = fi6; }
        if (cg == 7) { wV[wbase + 7] = fv7; wI[wbase + 7] = fi7; }
        __syncthreads();
        if (t < RPW) {
            const float v0 = wV[t];      const int i0 = wI[t];        // cods 0-511
            const float v1 = wV[32 + t]; const int i1 = wI[32 + t];   // cods 512-1023
            const int gi = (v1 > v0) ? i1 : i0;   // tie -> lower index (ch0) = first max
            sIdx[t] = gi;
            out[(size_t)IDX_OFF + (size_t)q * NROWS + base + t] = (float)gi;
        }
        __syncthreads();

        // residual update + loss: thread -> row r32, k-slice kpart*32..+32
        {
            const int gi = sIdx[r32];
            const float* qrow = cbq + (size_t)gi * DN + (kpart << 5);
#pragma unroll
            for (int i = 0; i < 8; ++i) {
                const float4 qv = *reinterpret_cast<const float4*>(qrow + (i << 2));
                const int k0 = (kpart << 5) + (i << 2);
                const float v0 = At[k0 + 0][r32] - qv.x;
                const float v1 = At[k0 + 1][r32] - qv.y;
                const float v2 = At[k0 + 2][r32] - qv.z;
                const float v3 = At[k0 + 3][r32] - qv.w;
                At[k0 + 0][r32] = v0;
                At[k0 + 1][r32] = v1;
                At[k0 + 2][r32] = v2;
                At[k0 + 3][r32] = v3;
                lossAcc += v0 * v0 + v1 * v1 + v2 * v2 + v3 * v3;
            }
        }
        __syncthreads();                 // At updated + sIdx/wV free before next stage
    }

    // quantized_sum = inputs - residual_final
#pragma unroll
    for (int i = 0; i < 8; ++i) {
        const int k0 = (kpart << 5) + (i << 2);
        const float4 v = *reinterpret_cast<const float4*>(in + (size_t)(base + r32) * DN + k0);
        float4 o;
        o.x = v.x - At[k0 + 0][r32];
        o.y = v.y - At[k0 + 1][r32];
        o.z = v.z - At[k0 + 2][r32];
        o.w = v.w - At[k0 + 3][r32];
        *reinterpret_cast<float4*>(out + (size_t)(base + r32) * DN + k0) = o;
    }

    // loss: wave butterfly + cross-wave via LDS + one atomic per WG
#pragma unroll
    for (int m = 1; m < 64; m <<= 1) lossAcc += __shfl_xor(lossAcc, m, 64);
    if ((t & 63) == 0) red[t >> 6] = lossAcc;
    __syncthreads();
    if (t == 0) {
        const float tot = red[0] + red[1] + red[2] + red[3];
        atomicAdd(out + LOSS_OFF, tot * (1.25f / (8.0f * 8388608.0f)));
    }
}

extern "C" void kernel_launch(void* const* d_in, const int* in_sizes, int n_in,
                              void* d_out, int out_size, void* d_ws, size_t ws_size,
                              hipStream_t stream) {
    (void)in_sizes; (void)n_in; (void)out_size; (void)ws_size;
    const float* in   = (const float*)d_in[0];
    const float* cb   = (const float*)d_in[1];
    float* out        = (float*)d_out;
    float* cbnt       = (float*)d_ws;   // 8 MiB scratch: normalized+transposed codebooks

    rvq_normalize_cb<<<dim3(2048), dim3(256), 0, stream>>>(cb, cbnt, out);
    rvq_main<<<dim3(1024), dim3(256), 0, stream>>>(in, cb, cbnt, out);
}

// Round 9
// 1670.554 us; speedup vs baseline: 1.3532x; 1.3532x over previous
//
#include <hip/hip_runtime.h>
#include <math.h>

#define QN 8
#define CN 1024
#define DN 256
#define NROWS 32768
#define RPW 64

#define LOSS_OFF 8388608
#define IDX_OFF  8388609

typedef float f2 __attribute__((ext_vector_type(2)));
typedef float f4 __attribute__((ext_vector_type(4)));

// ---------------------------------------------------------------------------
// Kernel 1: normalize codebooks, store transposed: cbnt[q][k][c]
// (unchanged from rounds 1-8 — verified correct)
// ---------------------------------------------------------------------------
__global__ void rvq_normalize_cb(const float* __restrict__ cb,
                                 float* __restrict__ cbnt,
                                 float* __restrict__ out) {
    if (blockIdx.x == 0 && threadIdx.x == 0) out[LOSS_OFF] = 0.0f;
    const int wave = threadIdx.x >> 6;
    const int lane = threadIdx.x & 63;
    const int cw = blockIdx.x * 4 + wave;          // 0..8191
    const int q = cw >> 10;
    const int c = cw & (CN - 1);
    float4 v = reinterpret_cast<const float4*>(cb + (size_t)cw * DN)[lane];
    float ss = v.x * v.x + v.y * v.y + v.z * v.z + v.w * v.w;
#pragma unroll
    for (int m = 1; m < 64; m <<= 1) ss += __shfl_xor(ss, m, 64);
    const float inv = 1.0f / fmaxf(sqrtf(ss), 1e-12f);
    float* dst = cbnt + (size_t)q * (DN * CN) + (size_t)(lane * 4) * CN + c;
    dst[0 * CN] = v.x * inv;
    dst[1 * CN] = v.y * inv;
    dst[2 * CN] = v.z * inv;
    dst[3 * CN] = v.w * inv;
}

// async global->LDS, 16B per lane (dest = wave-uniform base + lane*16)
__device__ __forceinline__ void acp16(float* lds_dst, const float* gsrc) {
    __builtin_amdgcn_global_load_lds(
        (const __attribute__((address_space(1))) unsigned int*)gsrc,
        (__attribute__((address_space(3))) unsigned int*)lds_dst, 16, 0, 0);
}

// v_pk_fma_f32: two independent IEEE f32 FMAs per instruction.
// A broadcast via op_sel: LO variant uses A-pair's .lo for both halves,
// HI variant uses .hi for both halves. acc/b use natural lo/hi mapping.
// Each (row,cod) accumulator chain stays a sequential fmaf chain -> numerics
// bit-identical to the scalar-fmaf rounds 2/4 that passed validation.
#define PKFMA_LO(acc, ap, bp) \
    asm("v_pk_fma_f32 %0, %1, %2, %0 op_sel:[0,0,0] op_sel_hi:[0,1,1]" \
        : "+v"(acc) : "v"(ap), "v"(bp));
#define PKFMA_HI(acc, ap, bp) \
    asm("v_pk_fma_f32 %0, %1, %2, %0 op_sel:[1,0,0] op_sel_hi:[1,1,1]" \
        : "+v"(acc) : "v"(ap), "v"(bp));

// 8 rows x 16 cods per thread: 64 named f2 accumulators (128 f32 — round-4 budget)
#define DECL_ROW(j) \
    f2 c##j##_0 = {0.f,0.f}, c##j##_1 = {0.f,0.f}, c##j##_2 = {0.f,0.f}, \
       c##j##_3 = {0.f,0.f}, c##j##_4 = {0.f,0.f}, c##j##_5 = {0.f,0.f}, \
       c##j##_6 = {0.f,0.f}, c##j##_7 = {0.f,0.f};

// one B-pair against all 8 rows (A pairs a01,a23,a45,a67; even row=LO, odd=HI)
#define PK_BP(p, bp) \
    PKFMA_LO(c0_##p, a01, bp) PKFMA_HI(c1_##p, a01, bp) \
    PKFMA_LO(c2_##p, a23, bp) PKFMA_HI(c3_##p, a23, bp) \
    PKFMA_LO(c4_##p, a45, bp) PKFMA_HI(c5_##p, a45, bp) \
    PKFMA_LO(c6_##p, a67, bp) PKFMA_HI(c7_##p, a67, bp)

#define KKSTEP(kk) { \
    const f4 a0 = *reinterpret_cast<const f4*>(&At[kt4 + (kk)][ty8]); \
    const f4 a1 = *reinterpret_cast<const f4*>(&At[kt4 + (kk)][ty8 + 4]); \
    const f4 b0 = *reinterpret_cast<const f4*>(&Btl[bb][kk][tx4]); \
    const f4 b1 = *reinterpret_cast<const f4*>(&Btl[bb][kk][128 + tx4]); \
    const f4 b2 = *reinterpret_cast<const f4*>(&Btl[bb][kk][256 + tx4]); \
    const f4 b3 = *reinterpret_cast<const f4*>(&Btl[bb][kk][384 + tx4]); \
    const f2 a01 = a0.xy, a23 = a0.zw, a45 = a1.xy, a67 = a1.zw; \
    const f2 b0l = b0.xy, b0h = b0.zw, b1l = b1.xy, b1h = b1.zw; \
    const f2 b2l = b2.xy, b2h = b2.zw, b3l = b3.xy, b3h = b3.zw; \
    PK_BP(0, b0l) PK_BP(1, b0h) PK_BP(2, b1l) PK_BP(3, b1h) \
    PK_BP(4, b2l) PK_BP(5, b2h) PK_BP(6, b3l) PK_BP(7, b3h) }

// within-thread cods ascend: pair p covers cods (p/2)*128 + tx4 + (p&1)*2 + {0,1}
// (same visit order as round 4's float4 fold); strict > keeps first max
#define FOLD_P(j, p, off) { \
    const int cb_ = coff + (off); \
    if (c##j##_##p.x > bv) { bv = c##j##_##p.x; bi = cb_ + 0; } \
    if (c##j##_##p.y > bv) { bv = c##j##_##p.y; bi = cb_ + 1; } }

#define FOLDMERGE(j) { \
    float bv = -INFINITY; int bi = 0; \
    FOLD_P(j, 0, tx4)            FOLD_P(j, 1, tx4 + 2) \
    FOLD_P(j, 2, 128 + tx4)      FOLD_P(j, 3, 128 + tx4 + 2) \
    FOLD_P(j, 4, 256 + tx4)      FOLD_P(j, 5, 256 + tx4 + 2) \
    FOLD_P(j, 6, 384 + tx4)      FOLD_P(j, 7, 384 + tx4 + 2) \
    _Pragma("unroll") \
    for (int m = 1; m < 32; m <<= 1) { \
        const float ov = __shfl_xor(bv, m, 64); \
        const int   oi = __shfl_xor(bi, m, 64); \
        if (ov > bv || (ov == bv && oi < bi)) { bv = ov; bi = oi; } } \
    if (bv > rv##j) { rv##j = bv; ri##j = bi; } }

// stage one 4k x 512c B-tile (8 KiB): 2 acp16/thread, linear LDS dest
// (round-4 addressing, verified)
#define STAGE(nb, tile) { \
    const float* s_ = cbtq + (size_t)(((tile) * 4 + (t >> 7)) * 1024) + coff + ((t * 4) & 511); \
    acp16(Bflat + (nb) * 2048 + t * 4, s_); \
    acp16(Bflat + (nb) * 2048 + 1024 + t * 4, s_ + 2048); }

// ---------------------------------------------------------------------------
// Kernel 2: persistent RVQ, 256-thread WG owns 64 rows through all 8 stages.
// Round-4 structure (best verified: clean allocation, no spill) with the
// inner GEMM's 128 scalar fmaf/kk replaced by 64 v_pk_fma_f32.
// ---------------------------------------------------------------------------
__global__ __attribute__((amdgpu_flat_work_group_size(256, 256), amdgpu_waves_per_eu(2, 2)))
void rvq_main(const float* __restrict__ in,
              const float* __restrict__ cb,
              const float* __restrict__ cbnt,
              float* __restrict__ out) {
    __shared__ float At[DN][RPW];       // 64 KiB residual, transposed [k][row]
    __shared__ float Btl[2][4][512];    // 16 KiB: dbuf of 4k x 512c tiles
    float* Bflat = &Btl[0][0][0];
    int*   sIdx  = reinterpret_cast<int*>(Bflat);        // alias (64 ints)
    float* red   = Bflat + 64;                           // alias (4 floats)

    const int t    = threadIdx.x;
    const int lane = t & 63;
    const int kgrp = t >> 6;            // wave id 0..3 (elementwise phases)
    const int ty8  = (t >> 5) << 3;     // row-group base: 8 groups x 8 rows
    const int tx4  = (t & 31) << 2;     // cod-group base within 512-chunk
    const int tx   = t & 31;
    const int base = blockIdx.x * RPW;

    // residual := inputs (At writes 2-way bank aliased = free)
#pragma unroll
    for (int i = 0; i < 16; ++i) {
        const int kb = kgrp * 4 + i * 16;
        float4 v = *reinterpret_cast<const float4*>(in + (size_t)(base + lane) * DN + kb);
        At[kb + 0][lane] = v.x;
        At[kb + 1][lane] = v.y;
        At[kb + 2][lane] = v.z;
        At[kb + 3][lane] = v.w;
    }

    float lossAcc = 0.0f;

    for (int q = 0; q < QN; ++q) {
        const float* cbq  = cb   + (size_t)q * (CN * DN);
        const float* cbtq = cbnt + (size_t)q * (DN * CN);
        float rv0 = -INFINITY, rv1 = -INFINITY, rv2 = -INFINITY, rv3 = -INFINITY,
              rv4 = -INFINITY, rv5 = -INFINITY, rv6 = -INFINITY, rv7 = -INFINITY;
        int ri0 = 0, ri1 = 0, ri2 = 0, ri3 = 0, ri4 = 0, ri5 = 0, ri6 = 0, ri7 = 0;

        for (int chunk = 0; chunk < 2; ++chunk) {        // 2 x 512 cods
            const int coff = chunk << 9;
            DECL_ROW(0) DECL_ROW(1) DECL_ROW(2) DECL_ROW(3)
            DECL_ROW(4) DECL_ROW(5) DECL_ROW(6) DECL_ROW(7)

            STAGE(0, 0)                                  // prologue: tile 0 -> buf 0

            for (int tt = 0; tt < 64; ++tt) {            // 64 tiles x 4 k
                __syncthreads();                          // vmcnt drained: buf[tt&1] ready
                const int bb = tt & 1;
                if (tt < 63) STAGE(bb ^ 1, tt + 1)        // next tile; hides under FMAs
                const int kt4 = tt * 4;
                KKSTEP(0) KKSTEP(1) KKSTEP(2) KKSTEP(3)
            }

            FOLDMERGE(0) FOLDMERGE(1) FOLDMERGE(2) FOLDMERGE(3)
            FOLDMERGE(4) FOLDMERGE(5) FOLDMERGE(6) FOLDMERGE(7)
        }

        __syncthreads();                 // all Btl reads done before alias write
        if (tx == 0) {
            sIdx[ty8 + 0] = ri0; sIdx[ty8 + 1] = ri1;
            sIdx[ty8 + 2] = ri2; sIdx[ty8 + 3] = ri3;
            sIdx[ty8 + 4] = ri4; sIdx[ty8 + 5] = ri5;
            sIdx[ty8 + 6] = ri6; sIdx[ty8 + 7] = ri7;
        }
        __syncthreads();
        if (t < 64) out[(size_t)IDX_OFF + (size_t)q * NROWS + base + t] = (float)sIdx[t];

        // residual update + loss: r_new = r - cb[idx]; loss += r_new^2
        {
            const int gi = sIdx[lane];
            const float* qrow = cbq + (size_t)gi * DN;
#pragma unroll
            for (int i = 0; i < 16; ++i) {
                const int kb = kgrp * 4 + i * 16;
                const float4 qv = *reinterpret_cast<const float4*>(qrow + kb);
                const float r0 = At[kb + 0][lane] - qv.x;
                const float r1 = At[kb + 1][lane] - qv.y;
                const float r2 = At[kb + 2][lane] - qv.z;
                const float r3 = At[kb + 3][lane] - qv.w;
                At[kb + 0][lane] = r0;
                At[kb + 1][lane] = r1;
                At[kb + 2][lane] = r2;
                At[kb + 3][lane] = r3;
                lossAcc += r0 * r0 + r1 * r1 + r2 * r2 + r3 * r3;
            }
        }
        __syncthreads();                 // At updated + sIdx free before next stage
    }

    // quantized_sum = inputs - residual_final
#pragma unroll
    for (int i = 0; i < 16; ++i) {
        const int kb = kgrp * 4 + i * 16;
        const float4 v = *reinterpret_cast<const float4*>(in + (size_t)(base + lane) * DN + kb);
        float4 o;
        o.x = v.x - At[kb + 0][lane];
        o.y = v.y - At[kb + 1][lane];
        o.z = v.z - At[kb + 2][lane];
        o.w = v.w - At[kb + 3][lane];
        *reinterpret_cast<float4*>(out + (size_t)(base + lane) * DN + kb) = o;
    }

    // loss: wave butterfly + cross-wave via LDS + one atomic per WG
#pragma unroll
    for (int m = 1; m < 64; m <<= 1) lossAcc += __shfl_xor(lossAcc, m, 64);
    __syncthreads();
    if (lane == 0) red[kgrp] = lossAcc;
    __syncthreads();
    if (t == 0) {
        const float tot = red[0] + red[1] + red[2] + red[3];
        atomicAdd(out + LOSS_OFF, tot * (1.25f / (8.0f * 8388608.0f)));
    }
}

extern "C" void kernel_launch(void* const* d_in, const int* in_sizes, int n_in,
                              void* d_out, int out_size, void* d_ws, size_t ws_size,
                              hipStream_t stream) {
    (void)in_sizes; (void)n_in; (void)out_size; (void)ws_size;
    const float* in   = (const float*)d_in[0];
    const float* cb   = (const float*)d_in[1];
    float* out        = (float*)d_out;
    float* cbnt       = (float*)d_ws;   // 8 MiB scratch: normalized+transposed codebooks

    rvq_normalize_cb<<<dim3(2048), dim3(256), 0, stream>>>(cb, cbnt, out);
    rvq_main<<<dim3(512), dim3(256), 0, stream>>>(in, cb, cbnt, out);
}

// Round 10
// 1661.237 us; speedup vs baseline: 1.3608x; 1.0056x over previous
//
#include <hip/hip_runtime.h>
#include <math.h>

#define QN 8
#define CN 1024
#define DN 256
#define NROWS 32768
#define RPW 64

#define LOSS_OFF 8388608
#define IDX_OFF  8388609

typedef float f2 __attribute__((ext_vector_type(2)));
typedef float f4 __attribute__((ext_vector_type(4)));

// ---------------------------------------------------------------------------
// Kernel 1: normalize codebooks, store transposed: cbnt[q][k][c]
// (unchanged from rounds 1-9 — verified correct)
// ---------------------------------------------------------------------------
__global__ void rvq_normalize_cb(const float* __restrict__ cb,
                                 float* __restrict__ cbnt,
                                 float* __restrict__ out) {
    if (blockIdx.x == 0 && threadIdx.x == 0) out[LOSS_OFF] = 0.0f;
    const int wave = threadIdx.x >> 6;
    const int lane = threadIdx.x & 63;
    const int cw = blockIdx.x * 4 + wave;          // 0..8191
    const int q = cw >> 10;
    const int c = cw & (CN - 1);
    float4 v = reinterpret_cast<const float4*>(cb + (size_t)cw * DN)[lane];
    float ss = v.x * v.x + v.y * v.y + v.z * v.z + v.w * v.w;
#pragma unroll
    for (int m = 1; m < 64; m <<= 1) ss += __shfl_xor(ss, m, 64);
    const float inv = 1.0f / fmaxf(sqrtf(ss), 1e-12f);
    float* dst = cbnt + (size_t)q * (DN * CN) + (size_t)(lane * 4) * CN + c;
    dst[0 * CN] = v.x * inv;
    dst[1 * CN] = v.y * inv;
    dst[2 * CN] = v.z * inv;
    dst[3 * CN] = v.w * inv;
}

// async global->LDS, 16B per lane (dest = wave-uniform base + lane*16)
__device__ __forceinline__ void acp16(float* lds_dst, const float* gsrc) {
    __builtin_amdgcn_global_load_lds(
        (const __attribute__((address_space(1))) unsigned int*)gsrc,
        (__attribute__((address_space(3))) unsigned int*)lds_dst, 16, 0, 0);
}

// v_pk_fma_f32 (verified on HW in round 9): two independent IEEE f32 FMAs.
// LO: A.lo broadcast to both halves; HI: A.hi. B/C natural lo/hi.
#define PKFMA_LO(acc, ap, bp) \
    asm("v_pk_fma_f32 %0, %1, %2, %0 op_sel:[0,0,0] op_sel_hi:[0,1,1]" \
        : "+v"(acc) : "v"(ap), "v"(bp));
#define PKFMA_HI(acc, ap, bp) \
    asm("v_pk_fma_f32 %0, %1, %2, %0 op_sel:[1,0,0] op_sel_hi:[1,1,1]" \
        : "+v"(acc) : "v"(ap), "v"(bp));

// 16 rows x 8 cods per thread: 64 named f2 accumulators.
// Thread's cods in the 512-chunk: {tx4+0..3} and {256+tx4+0..3} (tx4 = lane*4).
#define DECL_R(r) \
    f2 c##r##_0 = {0.f,0.f}, c##r##_1 = {0.f,0.f}, \
       c##r##_2 = {0.f,0.f}, c##r##_3 = {0.f,0.f};

// row pair (ra even -> A.lo, rb odd -> A.hi) against all 4 B-pairs
#define PK_ROWPAIR(ra, rb, ap) \
    PKFMA_LO(c##ra##_0, ap, b0l) PKFMA_HI(c##rb##_0, ap, b0l) \
    PKFMA_LO(c##ra##_1, ap, b0h) PKFMA_HI(c##rb##_1, ap, b0h) \
    PKFMA_LO(c##ra##_2, ap, b1l) PKFMA_HI(c##rb##_2, ap, b1l) \
    PKFMA_LO(c##ra##_3, ap, b1h) PKFMA_HI(c##rb##_3, ap, b1h)

#define KKSTEP(kk) { \
    const f4 a0 = *reinterpret_cast<const f4*>(&At[kt4 + (kk)][w16]);      /* wave-uniform */ \
    const f4 a1 = *reinterpret_cast<const f4*>(&At[kt4 + (kk)][w16 + 4]); \
    const f4 a2 = *reinterpret_cast<const f4*>(&At[kt4 + (kk)][w16 + 8]); \
    const f4 a3 = *reinterpret_cast<const f4*>(&At[kt4 + (kk)][w16 + 12]); \
    const f4 b0 = *reinterpret_cast<const f4*>(&Btl[bb][kk][tx4]);         /* 1024B distinct */ \
    const f4 b1 = *reinterpret_cast<const f4*>(&Btl[bb][kk][256 + tx4]); \
    const f2 b0l = b0.xy, b0h = b0.zw, b1l = b1.xy, b1h = b1.zw; \
    const f2 a01 = a0.xy, a23 = a0.zw, a45 = a1.xy, a67 = a1.zw; \
    const f2 a89 = a2.xy, aAB = a2.zw, aCD = a3.xy, aEF = a3.zw; \
    PK_ROWPAIR(0, 1, a01)   PK_ROWPAIR(2, 3, a23) \
    PK_ROWPAIR(4, 5, a45)   PK_ROWPAIR(6, 7, a67) \
    PK_ROWPAIR(8, 9, a89)   PK_ROWPAIR(10, 11, aAB) \
    PK_ROWPAIR(12, 13, aCD) PK_ROWPAIR(14, 15, aEF) }

// within-thread cods ascend (+0,1,2,3,256,257,258,259); strict > keeps first max.
// full 64-lane butterfly (rows are wave-uniform); tie -> lower index.
#define FOLDMERGE(r) { \
    float bv = -INFINITY; int bi = 0; \
    const int cb_ = coff + tx4; \
    if (c##r##_0.x > bv) { bv = c##r##_0.x; bi = cb_ + 0; } \
    if (c##r##_0.y > bv) { bv = c##r##_0.y; bi = cb_ + 1; } \
    if (c##r##_1.x > bv) { bv = c##r##_1.x; bi = cb_ + 2; } \
    if (c##r##_1.y > bv) { bv = c##r##_1.y; bi = cb_ + 3; } \
    if (c##r##_2.x > bv) { bv = c##r##_2.x; bi = cb_ + 256; } \
    if (c##r##_2.y > bv) { bv = c##r##_2.y; bi = cb_ + 257; } \
    if (c##r##_3.x > bv) { bv = c##r##_3.x; bi = cb_ + 258; } \
    if (c##r##_3.y > bv) { bv = c##r##_3.y; bi = cb_ + 259; } \
    _Pragma("unroll") \
    for (int m = 1; m < 64; m <<= 1) { \
        const float ov = __shfl_xor(bv, m, 64); \
        const int   oi = __shfl_xor(bi, m, 64); \
        if (ov > bv || (ov == bv && oi < bi)) { bv = ov; bi = oi; } } \
    if (bv > rv##r) { rv##r = bv; ri##r = bi; } }

// stage one 4k x 512c B-tile (8 KiB): 2 acp16/thread, linear LDS dest
// (rounds 4/9 addressing, verified)
#define STAGE(nb, tile) { \
    const float* s_ = cbtq + (size_t)(((tile) * 4 + (t >> 7)) * 1024) + coff + ((t * 4) & 511); \
    acp16(Bflat + (nb) * 2048 + t * 4, s_); \
    acp16(Bflat + (nb) * 2048 + 1024 + t * 4, s_ + 2048); }

// ---------------------------------------------------------------------------
// Kernel 2: persistent RVQ, 256-thread WG owns 64 rows through all 8 stages.
// GEMM mapping: wave w owns rows w*16..+15 (A-reads wave-uniform broadcasts),
// cods span all 64 lanes (B b128 reads move 1024 distinct bytes each).
// fmaf chain per (row,cod) is k=0..255 sequential — bit-identical to rounds 2-9.
// ---------------------------------------------------------------------------
__global__ __attribute__((amdgpu_flat_work_group_size(256, 256), amdgpu_waves_per_eu(2, 2)))
void rvq_main(const float* __restrict__ in,
              const float* __restrict__ cb,
              const float* __restrict__ cbnt,
              float* __restrict__ out) {
    __shared__ float At[DN][RPW];       // 64 KiB residual, transposed [k][row]
    __shared__ float Btl[2][4][512];    // 16 KiB: dbuf of 4k x 512c tiles
    float* Bflat = &Btl[0][0][0];
    int*   sIdx  = reinterpret_cast<int*>(Bflat);        // alias (64 ints)
    float* red   = Bflat + 64;                           // alias (4 floats)

    const int t    = threadIdx.x;
    const int lane = t & 63;
    const int kgrp = t >> 6;            // wave id 0..3
    const int w16  = kgrp << 4;         // GEMM row base: wave owns rows w16..w16+15
    const int tx4  = lane << 2;         // cod-group base within 512-chunk
    const int base = blockIdx.x * RPW;

    // residual := inputs (At writes 2-way bank aliased = free)
#pragma unroll
    for (int i = 0; i < 16; ++i) {
        const int kb = kgrp * 4 + i * 16;
        float4 v = *reinterpret_cast<const float4*>(in + (size_t)(base + lane) * DN + kb);
        At[kb + 0][lane] = v.x;
        At[kb + 1][lane] = v.y;
        At[kb + 2][lane] = v.z;
        At[kb + 3][lane] = v.w;
    }

    float lossAcc = 0.0f;

    for (int q = 0; q < QN; ++q) {
        const float* cbq  = cb   + (size_t)q * (CN * DN);
        const float* cbtq = cbnt + (size_t)q * (DN * CN);
        float rv0 = -INFINITY, rv1 = -INFINITY, rv2 = -INFINITY, rv3 = -INFINITY,
              rv4 = -INFINITY, rv5 = -INFINITY, rv6 = -INFINITY, rv7 = -INFINITY,
              rv8 = -INFINITY, rv9 = -INFINITY, rv10 = -INFINITY, rv11 = -INFINITY,
              rv12 = -INFINITY, rv13 = -INFINITY, rv14 = -INFINITY, rv15 = -INFINITY;
        int ri0 = 0, ri1 = 0, ri2 = 0, ri3 = 0, ri4 = 0, ri5 = 0, ri6 = 0, ri7 = 0,
            ri8 = 0, ri9 = 0, ri10 = 0, ri11 = 0, ri12 = 0, ri13 = 0, ri14 = 0, ri15 = 0;

        for (int chunk = 0; chunk < 2; ++chunk) {        // 2 x 512 cods
            const int coff = chunk << 9;
            DECL_R(0)  DECL_R(1)  DECL_R(2)  DECL_R(3)
            DECL_R(4)  DECL_R(5)  DECL_R(6)  DECL_R(7)
            DECL_R(8)  DECL_R(9)  DECL_R(10) DECL_R(11)
            DECL_R(12) DECL_R(13) DECL_R(14) DECL_R(15)

            STAGE(0, 0)                                  // prologue: tile 0 -> buf 0

            for (int tt = 0; tt < 64; ++tt) {            // 64 tiles x 4 k
                __syncthreads();                          // vmcnt drained: buf[tt&1] ready
                const int bb = tt & 1;
                if (tt < 63) STAGE(bb ^ 1, tt + 1)        // next tile; hides under FMAs
                const int kt4 = tt * 4;
                KKSTEP(0) KKSTEP(1) KKSTEP(2) KKSTEP(3)
            }

            FOLDMERGE(0)  FOLDMERGE(1)  FOLDMERGE(2)  FOLDMERGE(3)
            FOLDMERGE(4)  FOLDMERGE(5)  FOLDMERGE(6)  FOLDMERGE(7)
            FOLDMERGE(8)  FOLDMERGE(9)  FOLDMERGE(10) FOLDMERGE(11)
            FOLDMERGE(12) FOLDMERGE(13) FOLDMERGE(14) FOLDMERGE(15)
        }

        __syncthreads();                 // all Btl reads done before alias write
        if (lane == 0) {
            sIdx[w16 + 0]  = ri0;  sIdx[w16 + 1]  = ri1;
            sIdx[w16 + 2]  = ri2;  sIdx[w16 + 3]  = ri3;
            sIdx[w16 + 4]  = ri4;  sIdx[w16 + 5]  = ri5;
            sIdx[w16 + 6]  = ri6;  sIdx[w16 + 7]  = ri7;
            sIdx[w16 + 8]  = ri8;  sIdx[w16 + 9]  = ri9;
            sIdx[w16 + 10] = ri10; sIdx[w16 + 11] = ri11;
            sIdx[w16 + 12] = ri12; sIdx[w16 + 13] = ri13;
            sIdx[w16 + 14] = ri14; sIdx[w16 + 15] = ri15;
        }
        __syncthreads();
        if (t < 64) out[(size_t)IDX_OFF + (size_t)q * NROWS + base + t] = (float)sIdx[t];

        // residual update + loss: r_new = r - cb[idx]; loss += r_new^2
        {
            const int gi = sIdx[lane];
            const float* qrow = cbq + (size_t)gi * DN;
#pragma unroll
            for (int i = 0; i < 16; ++i) {
                const int kb = kgrp * 4 + i * 16;
                const float4 qv = *reinterpret_cast<const float4*>(qrow + kb);
                const float r0 = At[kb + 0][lane] - qv.x;
                const float r1 = At[kb + 1][lane] - qv.y;
                const float r2 = At[kb + 2][lane] - qv.z;
                const float r3 = At[kb + 3][lane] - qv.w;
                At[kb + 0][lane] = r0;
                At[kb + 1][lane] = r1;
                At[kb + 2][lane] = r2;
                At[kb + 3][lane] = r3;
                lossAcc += r0 * r0 + r1 * r1 + r2 * r2 + r3 * r3;
            }
        }
        __syncthreads();                 // At updated + sIdx free before next stage
    }

    // quantized_sum = inputs - residual_final
#pragma unroll
    for (int i = 0; i < 16; ++i) {
        const int kb = kgrp * 4 + i * 16;
        const float4 v = *reinterpret_cast<const float4*>(in + (size_t)(base + lane) * DN + kb);
        float4 o;
        o.x = v.x - At[kb + 0][lane];
        o.y = v.y - At[kb + 1][lane];
        o.z = v.z - At[kb + 2][lane];
        o.w = v.w - At[kb + 3][lane];
        *reinterpret_cast<float4*>(out + (size_t)(base + lane) * DN + kb) = o;
    }

    // loss: wave butterfly + cross-wave via LDS + one atomic per WG
#pragma unroll
    for (int m = 1; m < 64; m <<= 1) lossAcc += __shfl_xor(lossAcc, m, 64);
    __syncthreads();
    if (lane == 0) red[kgrp] = lossAcc;
    __syncthreads();
    if (t == 0) {
        const float tot = red[0] + red[1] + red[2] + red[3];
        atomicAdd(out + LOSS_OFF, tot * (1.25f / (8.0f * 8388608.0f)));
    }
}

extern "C" void kernel_launch(void* const* d_in, const int* in_sizes, int n_in,
                              void* d_out, int out_size, void* d_ws, size_t ws_size,
                              hipStream_t stream) {
    (void)in_sizes; (void)n_in; (void)out_size; (void)ws_size;
    const float* in   = (const float*)d_in[0];
    const float* cb   = (const float*)d_in[1];
    float* out        = (float*)d_out;
    float* cbnt       = (float*)d_ws;   // 8 MiB scratch: normalized+transposed codebooks

    rvq_normalize_cb<<<dim3(2048), dim3(256), 0, stream>>>(cb, cbnt, out);
    rvq_main<<<dim3(512), dim3(256), 0, stream>>>(in, cb, cbnt, out);
}

// Round 11
// 1637.320 us; speedup vs baseline: 1.3806x; 1.0146x over previous
//
#include <hip/hip_runtime.h>
#include <math.h>

#define QN 8
#define CN 1024
#define DN 256
#define NROWS 32768
#define RPW 64

#define LOSS_OFF 8388608
#define IDX_OFF  8388609

typedef float f2 __attribute__((ext_vector_type(2)));
typedef float f4 __attribute__((ext_vector_type(4)));

// ---------------------------------------------------------------------------
// Kernel 1: normalize codebooks, store transposed: cbnt[q][k][c]
// (unchanged from rounds 1-10 — verified correct)
// ---------------------------------------------------------------------------
__global__ void rvq_normalize_cb(const float* __restrict__ cb,
                                 float* __restrict__ cbnt,
                                 float* __restrict__ out) {
    if (blockIdx.x == 0 && threadIdx.x == 0) out[LOSS_OFF] = 0.0f;
    const int wave = threadIdx.x >> 6;
    const int lane = threadIdx.x & 63;
    const int cw = blockIdx.x * 4 + wave;          // 0..8191
    const int q = cw >> 10;
    const int c = cw & (CN - 1);
    float4 v = reinterpret_cast<const float4*>(cb + (size_t)cw * DN)[lane];
    float ss = v.x * v.x + v.y * v.y + v.z * v.z + v.w * v.w;
#pragma unroll
    for (int m = 1; m < 64; m <<= 1) ss += __shfl_xor(ss, m, 64);
    const float inv = 1.0f / fmaxf(sqrtf(ss), 1e-12f);
    float* dst = cbnt + (size_t)q * (DN * CN) + (size_t)(lane * 4) * CN + c;
    dst[0 * CN] = v.x * inv;
    dst[1 * CN] = v.y * inv;
    dst[2 * CN] = v.z * inv;
    dst[3 * CN] = v.w * inv;
}

// v_pk_fma_f32 (HW-verified rounds 9/10): two independent IEEE f32 FMAs.
// LO: A.lo broadcast to both halves; HI: A.hi. B/C natural lo/hi.
#define PKFMA_LO(acc, ap, bp) \
    asm("v_pk_fma_f32 %0, %1, %2, %0 op_sel:[0,0,0] op_sel_hi:[0,1,1]" \
        : "+v"(acc) : "v"(ap), "v"(bp));
#define PKFMA_HI(acc, ap, bp) \
    asm("v_pk_fma_f32 %0, %1, %2, %0 op_sel:[1,0,0] op_sel_hi:[1,1,1]" \
        : "+v"(acc) : "v"(ap), "v"(bp));

// 16 rows x 8 cods per thread: 64 named f2 accumulators.
// Thread's cods in the 512-chunk: {tx4+0..3} (c_0,c_1) and {256+tx4+0..3} (c_2,c_3).
#define DECL_R(r) \
    f2 c##r##_0 = {0.f,0.f}, c##r##_1 = {0.f,0.f}, \
       c##r##_2 = {0.f,0.f}, c##r##_3 = {0.f,0.f};

// row pair (ra even -> A.lo, rb odd -> A.hi) against the 4 B-pairs
#define PK_ROWPAIR(ra, rb, ap) \
    PKFMA_LO(c##ra##_0, ap, b0l) PKFMA_HI(c##rb##_0, ap, b0l) \
    PKFMA_LO(c##ra##_1, ap, b0h) PKFMA_HI(c##rb##_1, ap, b0h) \
    PKFMA_LO(c##ra##_2, ap, b1l) PKFMA_HI(c##rb##_2, ap, b1l) \
    PKFMA_LO(c##ra##_3, ap, b1h) PKFMA_HI(c##rb##_3, ap, b1h)

// one k-step: A from LDS (wave-uniform broadcasts), B from prefetched regs
#define KKR(kt, bA, bB) { \
    const f4 a0 = *reinterpret_cast<const f4*>(&At[(kt)][w16]); \
    const f4 a1 = *reinterpret_cast<const f4*>(&At[(kt)][w16 + 4]); \
    const f4 a2 = *reinterpret_cast<const f4*>(&At[(kt)][w16 + 8]); \
    const f4 a3 = *reinterpret_cast<const f4*>(&At[(kt)][w16 + 12]); \
    const f2 b0l = (bA).xy, b0h = (bA).zw, b1l = (bB).xy, b1h = (bB).zw; \
    const f2 a01 = a0.xy, a23 = a0.zw, a45 = a1.xy, a67 = a1.zw; \
    const f2 a89 = a2.xy, aAB = a2.zw, aCD = a3.xy, aEF = a3.zw; \
    PK_ROWPAIR(0, 1, a01)   PK_ROWPAIR(2, 3, a23) \
    PK_ROWPAIR(4, 5, a45)   PK_ROWPAIR(6, 7, a67) \
    PK_ROWPAIR(8, 9, a89)   PK_ROWPAIR(10, 11, aAB) \
    PK_ROWPAIR(12, 13, aCD) PK_ROWPAIR(14, 15, aEF) }

// load half-tile (2 k-steps) of B straight from global into named regs:
// per k: cods [coff+tx4 .. +3] and [coff+256+tx4 .. +3] — coalesced 16B/lane
#define LOADH(s, tile, h) { \
    const float* g_ = gB + ((size_t)(tile) << 12) + ((h) << 11); \
    b##s##0 = *reinterpret_cast<const f4*>(g_); \
    d##s##0 = *reinterpret_cast<const f4*>(g_ + 256); \
    b##s##1 = *reinterpret_cast<const f4*>(g_ + 1024); \
    d##s##1 = *reinterpret_cast<const f4*>(g_ + 1280); }

// within-thread cods ascend (+0,1,2,3,256,257,258,259); strict > keeps first max.
// full 64-lane butterfly (rows are wave-uniform); tie -> lower index.
#define FOLDMERGE(r) { \
    float bv = -INFINITY; int bi = 0; \
    const int cb_ = coff + tx4; \
    if (c##r##_0.x > bv) { bv = c##r##_0.x; bi = cb_ + 0; } \
    if (c##r##_0.y > bv) { bv = c##r##_0.y; bi = cb_ + 1; } \
    if (c##r##_1.x > bv) { bv = c##r##_1.x; bi = cb_ + 2; } \
    if (c##r##_1.y > bv) { bv = c##r##_1.y; bi = cb_ + 3; } \
    if (c##r##_2.x > bv) { bv = c##r##_2.x; bi = cb_ + 256; } \
    if (c##r##_2.y > bv) { bv = c##r##_2.y; bi = cb_ + 257; } \
    if (c##r##_3.x > bv) { bv = c##r##_3.x; bi = cb_ + 258; } \
    if (c##r##_3.y > bv) { bv = c##r##_3.y; bi = cb_ + 259; } \
    _Pragma("unroll") \
    for (int m = 1; m < 64; m <<= 1) { \
        const float ov = __shfl_xor(bv, m, 64); \
        const int   oi = __shfl_xor(bi, m, 64); \
        if (ov > bv || (ov == bv && oi < bi)) { bv = ov; bi = oi; } } \
    if (bv > rv##r) { rv##r = bv; ri##r = bi; } }

// ---------------------------------------------------------------------------
// Kernel 2: persistent RVQ, 256-thread WG owns 64 rows through all 8 stages.
// B-operands read straight from global (L2-resident) into registers with
// half-tile software pipelining — NO B staging, NO per-tile barriers.
// LDS holds only the residual At[k][row]; A-reads are wave-uniform broadcasts.
// fmaf/pk chain per (row,cod) is k=0..255 sequential — bit-identical to r2-r10.
// ---------------------------------------------------------------------------
__global__ __attribute__((amdgpu_flat_work_group_size(256, 256), amdgpu_waves_per_eu(2, 2)))
void rvq_main(const float* __restrict__ in,
              const float* __restrict__ cb,
              const float* __restrict__ cbnt,
              float* __restrict__ out) {
    __shared__ float At[DN][RPW];       // 64 KiB residual, transposed [k][row]
    __shared__ int   sIdx[64];
    __shared__ float red[4];

    const int t    = threadIdx.x;
    const int lane = t & 63;
    const int kgrp = t >> 6;            // wave id 0..3
    const int w16  = kgrp << 4;         // GEMM row base: wave owns rows w16..w16+15
    const int tx4  = lane << 2;         // cod-group base within 512-chunk
    const int base = blockIdx.x * RPW;

    // residual := inputs (At writes 2-way bank aliased = free)
#pragma unroll
    for (int i = 0; i < 16; ++i) {
        const int kb = kgrp * 4 + i * 16;
        float4 v = *reinterpret_cast<const float4*>(in + (size_t)(base + lane) * DN + kb);
        At[kb + 0][lane] = v.x;
        At[kb + 1][lane] = v.y;
        At[kb + 2][lane] = v.z;
        At[kb + 3][lane] = v.w;
    }

    float lossAcc = 0.0f;

    for (int q = 0; q < QN; ++q) {
        const float* cbq  = cb   + (size_t)q * (CN * DN);
        const float* cbtq = cbnt + (size_t)q * (DN * CN);
        float rv0 = -INFINITY, rv1 = -INFINITY, rv2 = -INFINITY, rv3 = -INFINITY,
              rv4 = -INFINITY, rv5 = -INFINITY, rv6 = -INFINITY, rv7 = -INFINITY,
              rv8 = -INFINITY, rv9 = -INFINITY, rv10 = -INFINITY, rv11 = -INFINITY,
              rv12 = -INFINITY, rv13 = -INFINITY, rv14 = -INFINITY, rv15 = -INFINITY;
        int ri0 = 0, ri1 = 0, ri2 = 0, ri3 = 0, ri4 = 0, ri5 = 0, ri6 = 0, ri7 = 0,
            ri8 = 0, ri9 = 0, ri10 = 0, ri11 = 0, ri12 = 0, ri13 = 0, ri14 = 0, ri15 = 0;

        __syncthreads();                                 // At ready (init / prev update)

        for (int chunk = 0; chunk < 2; ++chunk) {        // 2 x 512 cods
            const int coff = chunk << 9;
            const float* gB = cbtq + coff + tx4;         // [k][1024] row-major
            DECL_R(0)  DECL_R(1)  DECL_R(2)  DECL_R(3)
            DECL_R(4)  DECL_R(5)  DECL_R(6)  DECL_R(7)
            DECL_R(8)  DECL_R(9)  DECL_R(10) DECL_R(11)
            DECL_R(12) DECL_R(13) DECL_R(14) DECL_R(15)

            f4 bA0, dA0, bA1, dA1, bB0, dB0, bB1, dB1;
            LOADH(A, 0, 0)                               // prologue: tile 0 both halves
            LOADH(B, 0, 1)

            for (int tt = 0; tt < 64; ++tt) {            // 64 tiles x 4 k, no barriers
                const int kt4 = tt << 2;
                KKR(kt4 + 0, bA0, dA0)
                KKR(kt4 + 1, bA1, dA1)
                if (tt < 63) LOADH(A, tt + 1, 0)         // lands under half-1 compute
                KKR(kt4 + 2, bB0, dB0)
                KKR(kt4 + 3, bB1, dB1)
                if (tt < 63) LOADH(B, tt + 1, 1)         // lands under next half-0 compute
            }

            FOLDMERGE(0)  FOLDMERGE(1)  FOLDMERGE(2)  FOLDMERGE(3)
            FOLDMERGE(4)  FOLDMERGE(5)  FOLDMERGE(6)  FOLDMERGE(7)
            FOLDMERGE(8)  FOLDMERGE(9)  FOLDMERGE(10) FOLDMERGE(11)
            FOLDMERGE(12) FOLDMERGE(13) FOLDMERGE(14) FOLDMERGE(15)
        }

        if (lane == 0) {                 // per-wave-owned slots, no pre-barrier needed
            sIdx[w16 + 0]  = ri0;  sIdx[w16 + 1]  = ri1;
            sIdx[w16 + 2]  = ri2;  sIdx[w16 + 3]  = ri3;
            sIdx[w16 + 4]  = ri4;  sIdx[w16 + 5]  = ri5;
            sIdx[w16 + 6]  = ri6;  sIdx[w16 + 7]  = ri7;
            sIdx[w16 + 8]  = ri8;  sIdx[w16 + 9]  = ri9;
            sIdx[w16 + 10] = ri10; sIdx[w16 + 11] = ri11;
            sIdx[w16 + 12] = ri12; sIdx[w16 + 13] = ri13;
            sIdx[w16 + 14] = ri14; sIdx[w16 + 15] = ri15;
        }
        __syncthreads();
        if (t < 64) out[(size_t)IDX_OFF + (size_t)q * NROWS + base + t] = (float)sIdx[t];

        // residual update + loss: r_new = r - cb[idx]; loss += r_new^2
        {
            const int gi = sIdx[lane];
            const float* qrow = cbq + (size_t)gi * DN;
#pragma unroll
            for (int i = 0; i < 16; ++i) {
                const int kb = kgrp * 4 + i * 16;
                const float4 qv = *reinterpret_cast<const float4*>(qrow + kb);
                const float r0 = At[kb + 0][lane] - qv.x;
                const float r1 = At[kb + 1][lane] - qv.y;
                const float r2 = At[kb + 2][lane] - qv.z;
                const float r3 = At[kb + 3][lane] - qv.w;
                At[kb + 0][lane] = r0;
                At[kb + 1][lane] = r1;
                At[kb + 2][lane] = r2;
                At[kb + 3][lane] = r3;
                lossAcc += r0 * r0 + r1 * r1 + r2 * r2 + r3 * r3;
            }
        }
        // next iteration's stage-top __syncthreads covers the At update
    }

    __syncthreads();

    // quantized_sum = inputs - residual_final
#pragma unroll
    for (int i = 0; i < 16; ++i) {
        const int kb = kgrp * 4 + i * 16;
        const float4 v = *reinterpret_cast<const float4*>(in + (size_t)(base + lane) * DN + kb);
        float4 o;
        o.x = v.x - At[kb + 0][lane];
        o.y = v.y - At[kb + 1][lane];
        o.z = v.z - At[kb + 2][lane];
        o.w = v.w - At[kb + 3][lane];
        *reinterpret_cast<float4*>(out + (size_t)(base + lane) * DN + kb) = o;
    }

    // loss: wave butterfly + cross-wave via LDS + one atomic per WG
#pragma unroll
    for (int m = 1; m < 64; m <<= 1) lossAcc += __shfl_xor(lossAcc, m, 64);
    if (lane == 0) red[kgrp] = lossAcc;
    __syncthreads();
    if (t == 0) {
        const float tot = red[0] + red[1] + red[2] + red[3];
        atomicAdd(out + LOSS_OFF, tot * (1.25f / (8.0f * 8388608.0f)));
    }
}

extern "C" void kernel_launch(void* const* d_in, const int* in_sizes, int n_in,
                              void* d_out, int out_size, void* d_ws, size_t ws_size,
                              hipStream_t stream) {
    (void)in_sizes; (void)n_in; (void)out_size; (void)ws_size;
    const float* in   = (const float*)d_in[0];
    const float* cb   = (const float*)d_in[1];
    float* out        = (float*)d_out;
    float* cbnt       = (float*)d_ws;   // 8 MiB scratch: normalized+transposed codebooks

    rvq_normalize_cb<<<dim3(2048), dim3(256), 0, stream>>>(cb, cbnt, out);
    rvq_main<<<dim3(512), dim3(256), 0, stream>>>(in, cb, cbnt, out);
}

// Round 15
// 848.210 us; speedup vs baseline: 2.6651x; 1.9303x over previous
//
#include <hip/hip_runtime.h>
#include <math.h>

#define QN 8
#define CN 1024
#define DN 256
#define NROWS 32768

#define LOSS_OFF 8388608
#define IDX_OFF  8388609

typedef float f32x4v __attribute__((ext_vector_type(4)));
typedef short v8s __attribute__((ext_vector_type(8)));
typedef unsigned short u16;
typedef unsigned short u16x8 __attribute__((ext_vector_type(8)));

__device__ __forceinline__ u16 bfr(float x) {            // f32 -> bf16 RNE (bit ops)
    unsigned u = __float_as_uint(x);
    u += 0x7FFFu + ((u >> 16) & 1u);
    return (u16)(u >> 16);
}
__device__ __forceinline__ float bfs(u16 h) { return __uint_as_float(((unsigned)h) << 16); }

__device__ __forceinline__ void acpB(u16* d, const u16* s) {
    __builtin_amdgcn_global_load_lds(
        (const __attribute__((address_space(1))) unsigned int*)s,
        (__attribute__((address_space(3))) unsigned int*)d, 16, 0, 0);
}

// ---------------------------------------------------------------------------
// Prep: normalize codebooks; store bf16 hi/mid planes AND the exact inv
// (1/max(||c||,eps)) used, so the main kernel's rerank can reproduce the
// rounds-1-11 sim chain bitwise.
// ---------------------------------------------------------------------------
__global__ void rvq_prep(const float* __restrict__ cb,
                         u16* __restrict__ bh, u16* __restrict__ bm,
                         float* __restrict__ invw,
                         float* __restrict__ out) {
    if (blockIdx.x == 0 && threadIdx.x == 0) out[LOSS_OFF] = 0.0f;
    const int wave = threadIdx.x >> 6;
    const int lane = threadIdx.x & 63;
    const int cw = blockIdx.x * 4 + wave;            // q*1024 + c
    float4 v = reinterpret_cast<const float4*>(cb + (size_t)cw * DN)[lane];
    float ss = v.x * v.x + v.y * v.y + v.z * v.z + v.w * v.w;
#pragma unroll
    for (int m = 1; m < 64; m <<= 1) ss += __shfl_xor(ss, m, 64);
    const float inv = 1.0f / fmaxf(sqrtf(ss), 1e-12f);
    if (lane == 0) invw[cw] = inv;
    ushort4 hv, mv;
#define PSPLIT(F, E) { const float x_ = (F) * inv; const u16 h_ = bfr(x_); \
                       hv.E = h_; mv.E = bfr(x_ - bfs(h_)); }
    PSPLIT(v.x, x) PSPLIT(v.y, y) PSPLIT(v.z, z) PSPLIT(v.w, w)
#undef PSPLIT
    reinterpret_cast<ushort4*>(bh + (size_t)cw * DN)[lane] = hv;
    reinterpret_cast<ushort4*>(bm + (size_t)cw * DN)[lane] = mv;
}

// ---------------------------------------------------------------------------
// Main: persistent RVQ, 256 thr / 64 rows per WG, 8 stages.
// MFMA bf16-split GEMM generates top-4 candidates per row; final selection is
// an EXACT replay of the rounds-1-11 scalar sim chain (sequential k=0..255
// fmaf of residual x (cb*inv)) -> bitwise-identical sims -> identical argmax.
// ---------------------------------------------------------------------------
__global__ __attribute__((amdgpu_flat_work_group_size(256, 256), amdgpu_waves_per_eu(2, 2)))
void rvq_main(const float* __restrict__ in,
              const float* __restrict__ cb,
              const u16* __restrict__ bh, const u16* __restrict__ bm,
              const float* __restrict__ invw,
              float* __restrict__ out) {
    __shared__ __align__(16) char lds[81920];
    u16* Ah = (u16*)lds;                        // [32 kb][64 row][8]  32 KB
    u16* Am = (u16*)(lds + 32768);              // 32 KB
    u16* Bt = (u16*)(lds + 65536);              // dbuf B tiles, 16 KB
    float* Rres = (float*)lds;                  // alias of Ah/Am: R[k][row] during rerank
    int*   cand = (int*)(lds + 65536);          // alias (64 rows x 4 cands = 1 KB)
    int*   sIdx = (int*)(lds + 65536 + 1024);   // 64 ints
    float* red  = (float*)(lds + 65536 + 1024 + 256);

    const int t   = threadIdx.x;
    const int l   = t & 63;
    const int w   = t >> 6;
    const int g   = l >> 4;
    const int li  = l & 15;
    const int row = l;                          // elementwise row
    const int KS  = w * 64;                     // elementwise k-slice base
    const int w8  = w * 8;
    const int w16 = w * 16;
    const int w16li = w16 + li;
    const int base  = blockIdx.x * 64;

    // residual := inputs, in registers (16 float4 per thread, k = KS + i*4)
    const float* inr0 = in + (size_t)(base + row) * DN + KS;
#define DECLR(i) float4 rr##i = *reinterpret_cast<const float4*>(inr0 + (i) * 4);
    DECLR(0) DECLR(1) DECLR(2) DECLR(3) DECLR(4) DECLR(5) DECLR(6) DECLR(7)
    DECLR(8) DECLR(9) DECLR(10) DECLR(11) DECLR(12) DECLR(13) DECLR(14) DECLR(15)
#undef DECLR
    float lossAcc = 0.0f;

    for (int qs = 0; qs < QN; ++qs) {
        const u16* bhq = bh + ((size_t)qs << 18);
        const u16* bmq = bm + ((size_t)qs << 18);

        // --- split residual into Ah/Am (bf16 hi/mid), layout [kb][row][8]
#define SCV(e, x) { const float xv_ = (x); const u16 hb_ = bfr(xv_); \
                    hh_[e] = hb_; mm_[e] = bfr(xv_ - bfs(hb_)); }
#define SPLITP(p, RA, RB) { u16x8 hh_, mm_; \
        SCV(0, RA.x) SCV(1, RA.y) SCV(2, RA.z) SCV(3, RA.w) \
        SCV(4, RB.x) SCV(5, RB.y) SCV(6, RB.z) SCV(7, RB.w) \
        const int ao_ = ((w8 + (p)) * 64 + row) * 8; \
        *(u16x8*)(Ah + ao_) = hh_; *(u16x8*)(Am + ao_) = mm_; }
        SPLITP(0, rr0, rr1)   SPLITP(1, rr2, rr3)   SPLITP(2, rr4, rr5)
        SPLITP(3, rr6, rr7)   SPLITP(4, rr8, rr9)   SPLITP(5, rr10, rr11)
        SPLITP(6, rr12, rr13) SPLITP(7, rr14, rr15)
#undef SPLITP
#undef SCV

#define STAGE(nb, sp_) { \
        _Pragma("unroll") \
        for (int jj_ = 0; jj_ < 2; ++jj_) { \
            const int d_ = jj_ * 256 + t; \
            const int sub_ = d_ >> 8, pl_ = (d_ >> 7) & 1, kb_ = (d_ >> 5) & 3, col_ = d_ & 31; \
            const int s2_ = (sp_) * 2 + sub_; const int cs2_ = s2_ >> 3, ks2_ = s2_ & 7; \
            const u16* gp_ = (pl_ ? bmq : bhq) + (size_t)(cs2_ * 32 + col_) * DN + ks2_ * 32 + kb_ * 8; \
            acpB(Bt + (nb) * 4096 + d_ * 8, gp_); } }

        // per-row top-4 state (descending v1>=v2>=v3>=v4)
#define DECLT(j) float v1_##j = -INFINITY, v2_##j = -INFINITY, \
                       v3_##j = -INFINITY, v4_##j = -INFINITY; \
                 int i1_##j = 0, i2_##j = 0, i3_##j = 0, i4_##j = 0;
        DECLT(0) DECLT(1) DECLT(2) DECLT(3)
#undef DECLT
        f32x4v accA = (f32x4v){0.f, 0.f, 0.f, 0.f};
        f32x4v accB = (f32x4v){0.f, 0.f, 0.f, 0.f};

#define MRG4(j, vv, ci) { const float v_ = (vv); const int c_ = (ci); \
        if (v_ > v4_##j) { \
            if (v_ > v2_##j) { \
                if (v_ > v1_##j) { v4_##j = v3_##j; i4_##j = i3_##j; v3_##j = v2_##j; i3_##j = i2_##j; \
                                   v2_##j = v1_##j; i2_##j = i1_##j; v1_##j = v_; i1_##j = c_; } \
                else             { v4_##j = v3_##j; i4_##j = i3_##j; v3_##j = v2_##j; i3_##j = i2_##j; \
                                   v2_##j = v_; i2_##j = c_; } \
            } else { \
                if (v_ > v3_##j) { v4_##j = v3_##j; i4_##j = i3_##j; v3_##j = v_; i3_##j = c_; } \
                else             { v4_##j = v_; i4_##j = c_; } \
            } } }

#define COMPUTE(bb, sub) { \
        const int s_ = sp * 2 + (sub); const int cs_ = s_ >> 3, ks_ = s_ & 7; \
        const int ao_ = ((ks_ * 4 + g) * 64 + w16li) * 8; \
        const v8s ah_ = *(const v8s*)(Ah + ao_); \
        const v8s am_ = *(const v8s*)(Am + ao_); \
        const u16* bt_ = Bt + ((bb) * 2 + (sub)) * 2048; \
        const v8s bh0_ = *(const v8s*)(bt_ + g * 256 + li * 8); \
        const v8s bh1_ = *(const v8s*)(bt_ + g * 256 + 128 + li * 8); \
        const v8s bm0_ = *(const v8s*)(bt_ + 1024 + g * 256 + li * 8); \
        const v8s bm1_ = *(const v8s*)(bt_ + 1024 + g * 256 + 128 + li * 8); \
        accA = __builtin_amdgcn_mfma_f32_16x16x32_bf16(ah_, bh0_, accA, 0, 0, 0); \
        accA = __builtin_amdgcn_mfma_f32_16x16x32_bf16(ah_, bm0_, accA, 0, 0, 0); \
        accA = __builtin_amdgcn_mfma_f32_16x16x32_bf16(am_, bh0_, accA, 0, 0, 0); \
        accA = __builtin_amdgcn_mfma_f32_16x16x32_bf16(am_, bm0_, accA, 0, 0, 0); \
        accB = __builtin_amdgcn_mfma_f32_16x16x32_bf16(ah_, bh1_, accB, 0, 0, 0); \
        accB = __builtin_amdgcn_mfma_f32_16x16x32_bf16(ah_, bm1_, accB, 0, 0, 0); \
        accB = __builtin_amdgcn_mfma_f32_16x16x32_bf16(am_, bh1_, accB, 0, 0, 0); \
        accB = __builtin_amdgcn_mfma_f32_16x16x32_bf16(am_, bm1_, accB, 0, 0, 0); \
        if (ks_ == 7) { \
            const int cb0_ = cs_ * 32 + li; \
            MRG4(0, accA.x, cb0_) MRG4(1, accA.y, cb0_) MRG4(2, accA.z, cb0_) MRG4(3, accA.w, cb0_) \
            MRG4(0, accB.x, cb0_ + 16) MRG4(1, accB.y, cb0_ + 16) \
            MRG4(2, accB.z, cb0_ + 16) MRG4(3, accB.w, cb0_ + 16) \
            accA = (f32x4v){0.f, 0.f, 0.f, 0.f}; accB = (f32x4v){0.f, 0.f, 0.f, 0.f}; } }

        STAGE(0, 0)
        for (int sp = 0; sp < 128; ++sp) {
            __syncthreads();
            const int bb = sp & 1;
            if (sp < 127) STAGE(bb ^ 1, sp + 1)
            COMPUTE(bb, 0)
            COMPUTE(bb, 1)
        }
#undef COMPUTE
#undef STAGE

        // --- global top-4 per row via masked butterfly extraction; write to cand[]
#define EXT1(j, GD) { \
        const float cv_ = (p_ == 0) ? v1_##j : (p_ == 1) ? v2_##j : \
                          (p_ == 2) ? v3_##j : (p_ == 3) ? v4_##j : -INFINITY; \
        const int   ci_ = (p_ == 0) ? i1_##j : (p_ == 1) ? i2_##j : \
                          (p_ == 2) ? i3_##j : i4_##j; \
        float bv_ = cv_; int bi_ = ci_; \
        _Pragma("unroll") \
        for (int m = 1; m < 16; m <<= 1) { \
            const float ov = __shfl_xor(bv_, m, 64); \
            const int   oi = __shfl_xor(bi_, m, 64); \
            if (ov > bv_ || (ov == bv_ && oi < bi_)) { bv_ = ov; bi_ = oi; } } \
        GD = bi_; if (p_ < 4 && ci_ == bi_) ++p_; }

#define EXTW(j) { \
        int p_ = 0; int g0_, g1_, g2_, g3_; \
        EXT1(j, g0_) EXT1(j, g1_) EXT1(j, g2_) EXT1(j, g3_) \
        if (li == 0) { int* cp_ = cand + (w16 + g * 4 + (j)) * 4; \
            cp_[0] = g0_; cp_[1] = g1_; cp_[2] = g2_; cp_[3] = g3_; } }
        EXTW(0) EXTW(1) EXTW(2) EXTW(3)
#undef EXTW
#undef EXT1
#undef MRG4

        __syncthreads();                 // GEMM reads of Ah/Am done; cand visible

        // --- dump residual registers to R[k][row] (bitwise rounds-1-11 values)
#define DMP(i) { const int k0_ = (KS + (i) * 4) * 64 + row; \
        Rres[k0_] = rr##i.x; Rres[k0_ + 64] = rr##i.y; \
        Rres[k0_ + 128] = rr##i.z; Rres[k0_ + 192] = rr##i.w; }
        DMP(0) DMP(1) DMP(2) DMP(3) DMP(4) DMP(5) DMP(6) DMP(7)
        DMP(8) DMP(9) DMP(10) DMP(11) DMP(12) DMP(13) DMP(14) DMP(15)
#undef DMP
        __syncthreads();                 // R + cand ready for chains

        // --- exact rerank: thread (row = t>>2, cd = t&3) replays the
        //     rounds-1-11 sequential sim chain for its candidate.
        {
            const int crow = t >> 2;
            const int c    = cand[(crow << 2) | (t & 3)];
            const float invc = invw[(qs << 10) + c];
            const float* cr = cb + ((size_t)qs << 18) + (size_t)c * DN;
            float acc = 0.0f;
#pragma unroll 8
            for (int kb = 0; kb < 64; ++kb) {
                const float4 cv = *reinterpret_cast<const float4*>(cr + kb * 4);
                const int k0 = kb * 256 + crow;          // (kb*4)*64 + crow
                acc = fmaf(Rres[k0 +   0], cv.x * invc, acc);
                acc = fmaf(Rres[k0 +  64], cv.y * invc, acc);
                acc = fmaf(Rres[k0 + 128], cv.z * invc, acc);
                acc = fmaf(Rres[k0 + 192], cv.w * invc, acc);
            }
            float sv = acc; int si = c;
#pragma unroll
            for (int m = 1; m < 4; m <<= 1) {
                const float ov = __shfl_xor(sv, m, 64);
                const int   oi = __shfl_xor(si, m, 64);
                if (ov > sv || (ov == sv && oi < si)) { sv = ov; si = oi; }
            }
            if ((t & 3) == 0) sIdx[crow] = si;
        }
        __syncthreads();
        if (t < 64) out[(size_t)IDX_OFF + (size_t)qs * NROWS + base + t] = (float)sIdx[t];

        // --- residual update + loss (registers; raw cb row)
        {
            const int gi = sIdx[row];
            const float* qr = cb + ((size_t)qs << 18) + (size_t)gi * DN + KS;
#define UPD(i) { const float4 qv = *reinterpret_cast<const float4*>(qr + (i) * 4); \
                 rr##i.x -= qv.x; rr##i.y -= qv.y; rr##i.z -= qv.z; rr##i.w -= qv.w; \
                 lossAcc += rr##i.x * rr##i.x + rr##i.y * rr##i.y \
                          + rr##i.z * rr##i.z + rr##i.w * rr##i.w; }
            UPD(0) UPD(1) UPD(2) UPD(3) UPD(4) UPD(5) UPD(6) UPD(7)
            UPD(8) UPD(9) UPD(10) UPD(11) UPD(12) UPD(13) UPD(14) UPD(15)
#undef UPD
        }
        __syncthreads();                 // R/sIdx reads done before next stage writes
    }

    // --- loss: wave butterfly + cross-wave + one atomic per WG
#pragma unroll
    for (int m = 1; m < 64; m <<= 1) lossAcc += __shfl_xor(lossAcc, m, 64);
    if (l == 0) red[w] = lossAcc;
    __syncthreads();
    if (t == 0) {
        const float tot = red[0] + red[1] + red[2] + red[3];
        atomicAdd(out + LOSS_OFF, tot * (1.25f / (8.0f * 8388608.0f)));
    }

    // --- quantized_sum = in - residual: transpose via LDS for coalesced writes
    float* Rf = (float*)lds;
    __syncthreads();
#define TW(i) *reinterpret_cast<float4*>(Rf + row * DN + KS + (i) * 4) = rr##i;
    TW(0) TW(1) TW(2) TW(3) TW(4) TW(5) TW(6) TW(7)
    TW(8) TW(9) TW(10) TW(11) TW(12) TW(13) TW(14) TW(15)
#undef TW
    __syncthreads();
    {
        const int row2 = t >> 2;
        const int kb2  = (t & 3) * 64;
        const float* ir = in + (size_t)(base + row2) * DN + kb2;
        float* orp = out + (size_t)(base + row2) * DN + kb2;
        const float* rf = Rf + row2 * DN + kb2;
#pragma unroll
        for (int i = 0; i < 16; ++i) {
            const float4 rv = *reinterpret_cast<const float4*>(rf + i * 4);
            const float4 iv = *reinterpret_cast<const float4*>(ir + i * 4);
            float4 ov;
            ov.x = iv.x - rv.x; ov.y = iv.y - rv.y;
            ov.z = iv.z - rv.z; ov.w = iv.w - rv.w;
            *reinterpret_cast<float4*>(orp + i * 4) = ov;
        }
    }
}

extern "C" void kernel_launch(void* const* d_in, const int* in_sizes, int n_in,
                              void* d_out, int out_size, void* d_ws, size_t ws_size,
                              hipStream_t stream) {
    (void)in_sizes; (void)n_in; (void)out_size; (void)ws_size;
    const float* in = (const float*)d_in[0];
    const float* cb = (const float*)d_in[1];
    float* out = (float*)d_out;
    u16* bhp = (u16*)d_ws;                          // 4.19 MB hi plane
    u16* bmp = bhp + (size_t)QN * CN * DN;          // 4.19 MB mid plane
    float* invw = (float*)(bmp + (size_t)QN * CN * DN);  // 32 KB inv table

    rvq_prep<<<dim3(2048), dim3(256), 0, stream>>>(cb, bhp, bmp, invw, out);
    rvq_main<<<dim3(512), dim3(256), 0, stream>>>(in, cb, bhp, bmp, invw, out);
}